// Round 8
// baseline (362.475 us; speedup 1.0000x reference)
//
#include <hip/hip_runtime.h>

#define CUR 512
#define FULLS 1024
#define BSZ 8
#define DIMM 1024
#define NH 16
#define HD 64

typedef __attribute__((ext_vector_type(8))) short short8;
typedef __attribute__((ext_vector_type(4))) float floatx4;

__device__ __forceinline__ unsigned short f2bf(float x) {
  unsigned int u = __float_as_uint(x);
  unsigned int r = (u + 0x7fffu + ((u >> 16) & 1u)) >> 16;
  return (unsigned short)r;
}
__device__ __forceinline__ float bf2f(unsigned short h) {
  return __uint_as_float(((unsigned int)h) << 16);
}

__device__ __forceinline__ void async16(void* lds, const void* g) {
  __builtin_amdgcn_global_load_lds(
      (const __attribute__((address_space(1))) unsigned int*)g,
      (__attribute__((address_space(3))) unsigned int*)lds, 16, 0, 0);
}

// ---------------------------------------------------------------------------
// Fused prep: all fp32->bf16 casts + weight transpose-casts in ONE launch.
// ---------------------------------------------------------------------------
__global__ __launch_bounds__(256)
void prep_kernel(const float* __restrict__ fi, short* __restrict__ fi_bf,
                 const float* __restrict__ inp, short* __restrict__ in_bf,
                 const float* __restrict__ pe, short* __restrict__ pe_bf,
                 const float* __restrict__ Wkv, short* __restrict__ Wkv_t,
                 const float* __restrict__ Wq, short* __restrict__ Wq_t,
                 const float* __restrict__ Wpos, short* __restrict__ Wpos_t,
                 const float* __restrict__ Wproj, short* __restrict__ Wproj_t) {
  __shared__ float t[64][65];
  const int blk = blockIdx.x;
  const int tid = threadIdx.x;
  if (blk < 6656) {
    const float* x; short* y; int base;
    if (blk < 4096)      { x = fi;  y = fi_bf; base = blk; }
    else if (blk < 6144) { x = inp; y = in_bf; base = blk - 4096; }
    else                 { x = pe;  y = pe_bf; base = blk - 6144; }
    int i = (base * 256 + tid) * 8;
    float a[8];
    *(float4*)&a[0] = *(const float4*)&x[i];
    *(float4*)&a[4] = *(const float4*)&x[i + 4];
    short8 o;
    #pragma unroll
    for (int j = 0; j < 8; ++j) o[j] = f2bf(a[j]);
    *(short8*)&y[i] = o;
    return;
  }
  const float* W; short* Wt; int N, t2;
  if (blk < 7168)      { W = Wkv;   Wt = Wkv_t;   N = 2048; t2 = blk - 6656; }
  else if (blk < 7424) { W = Wq;    Wt = Wq_t;    N = 1024; t2 = blk - 7168; }
  else if (blk < 7680) { W = Wpos;  Wt = Wpos_t;  N = 1024; t2 = blk - 7424; }
  else                 { W = Wproj; Wt = Wproj_t; N = 1024; t2 = blk - 7680; }
  const int K = 1024;
  const int nx = N / 64;
  const int n0 = (t2 % nx) * 64, k0 = (t2 / nx) * 64;
  #pragma unroll
  for (int r = 0; r < 4; ++r) {
    int f = tid + r * 256;
    int row = f >> 4, c = (f & 15) * 4;
    float4 v = *(const float4*)&W[(size_t)(k0 + row) * N + n0 + c];
    t[c + 0][row] = v.x; t[c + 1][row] = v.y;
    t[c + 2][row] = v.z; t[c + 3][row] = v.w;
  }
  __syncthreads();
  #pragma unroll
  for (int r = 0; r < 2; ++r) {
    int f = tid + r * 256;
    int row = f >> 3, c = (f & 7) * 8;
    short8 o;
    #pragma unroll
    for (int j = 0; j < 8; ++j) o[j] = f2bf(t[row][c + j]);
    *(short8*)&Wt[(size_t)(n0 + row) * K + k0 + c] = o;
  }
}

// ---------------------------------------------------------------------------
// bf16 MFMA GEMM body (m97 structure, 128x128 tile) — q/r/out GEMMs.
// ---------------------------------------------------------------------------
__device__ __forceinline__
void gemm_body(short* As, short* Bs,
               const short* __restrict__ A, const short* __restrict__ Bt,
               const float* __restrict__ bias, void* __restrict__ Cp,
               int M, int N, int K, int out_bf16, int bx, int by) {
  const int tid = threadIdx.x;
  const int w = tid >> 6, lane = tid & 63, l15 = lane & 15, quad = lane >> 4;
  const int m0 = by * 128, n0 = bx * 128;
  const int wm = (w & 1) * 64, wn = (w >> 1) * 64;

  floatx4 acc[4][4];
  #pragma unroll
  for (int i = 0; i < 4; ++i)
    #pragma unroll
    for (int j = 0; j < 4; ++j) acc[i][j] = (floatx4){0.f, 0.f, 0.f, 0.f};

  for (int k0 = 0; k0 < K; k0 += 32) {
    __syncthreads();
    #pragma unroll
    for (int rnd = 0; rnd < 2; ++rnd) {
      int fb = rnd * 256 + w * 64;
      int f = fb + lane;
      int row = f >> 2, c = f & 3;
      int cs = (c ^ (row & 3)) * 8;
      async16(As + fb * 8, &A[(size_t)(m0 + row) * K + k0 + cs]);
      async16(Bs + fb * 8, &Bt[(size_t)(n0 + row) * K + k0 + cs]);
    }
    __syncthreads();
    short8 af[4], bf[4];
    #pragma unroll
    for (int t = 0; t < 4; ++t) {
      int swz = ((quad ^ (l15 & 3)) * 8);
      af[t] = *(const short8*)&As[(wm + t * 16 + l15) * 32 + swz];
      bf[t] = *(const short8*)&Bs[(wn + t * 16 + l15) * 32 + swz];
    }
    #pragma unroll
    for (int mt = 0; mt < 4; ++mt)
      #pragma unroll
      for (int nt = 0; nt < 4; ++nt)
        acc[mt][nt] = __builtin_amdgcn_mfma_f32_16x16x32_bf16(
            af[mt], bf[nt], acc[mt][nt], 0, 0, 0);
  }

  #pragma unroll
  for (int mt = 0; mt < 4; ++mt)
    #pragma unroll
    for (int nt = 0; nt < 4; ++nt)
      #pragma unroll
      for (int r = 0; r < 4; ++r) {
        int row = m0 + wm + mt * 16 + quad * 4 + r;
        int col = n0 + wn + nt * 16 + l15;
        float v = acc[mt][nt][r] + bias[col];
        if (out_bf16) ((short*)Cp)[(size_t)row * N + col] = (short)f2bf(v);
        else          ((float*)Cp)[(size_t)row * N + col] = v;
      }
}

// ---------------------------------------------------------------------------
// kv-only 256x256-tile 8-phase bf16 GEMM. 256 blocks = one dispatch round.
// ---------------------------------------------------------------------------
__global__ __launch_bounds__(512, 2)
void proj_kv8_kernel(const short* __restrict__ A, const short* __restrict__ Bt,
                     const float* __restrict__ bias, short* __restrict__ Cp) {
  __shared__ __align__(16) short As[2][2][128 * 64];
  __shared__ __align__(16) short Bs[2][2][128 * 64];

  const int blk = blockIdx.x;
  const int xcd = blk & 7, l = blk >> 3;
  const int bx = (xcd & 1) * 4 + (l & 3);
  const int by = (xcd >> 1) * 8 + (l >> 2);
  const int N = 2048;

  const int tid = threadIdx.x;
  const int w = tid >> 6, lane = tid & 63, l15 = lane & 15, quad = lane >> 4;
  const int wmi = w >> 2, wni = w & 3;
  const int m0 = by * 256, n0 = bx * 256;
  const int brow0 = (wni & 1) * 64;
  constexpr int NT = 16;

  auto stage = [&](short* dst, const short* src) {
    #pragma unroll
    for (int rnd = 0; rnd < 2; ++rnd) {
      int fb = rnd * 512 + w * 64;
      int f = fb + lane;
      int row = f >> 3, c = f & 7;
      async16(dst + fb * 8, src + (size_t)row * 1024 + ((c ^ (row & 7)) << 3));
    }
  };
  auto srcA = [&](int tt, int h) { return A + ((size_t)(m0 + h * 128)) * 1024 + tt * 64; };
  auto srcB = [&](int tt, int h) { return Bt + ((size_t)(n0 + h * 128)) * 1024 + tt * 64; };

  stage(As[0][0], srcA(0, 0));
  stage(Bs[0][0], srcB(0, 0));
  stage(Bs[0][1], srcB(0, 1));
  stage(As[0][1], srcA(0, 1));
  stage(As[1][0], srcA(1, 0));
  stage(Bs[1][0], srcB(1, 0));
  stage(Bs[1][1], srcB(1, 1));
  asm volatile("s_waitcnt vmcnt(6)" ::: "memory");
  asm volatile("s_barrier" ::: "memory");

  floatx4 acc[8][4];
  #pragma unroll
  for (int i = 0; i < 8; ++i)
    #pragma unroll
    for (int j = 0; j < 4; ++j) acc[i][j] = (floatx4){0.f, 0.f, 0.f, 0.f};

  short8 af[4][2], bf0[2][2], bf1[2][2];

  #pragma unroll 1
  for (int t = 0; t < NT; ++t) {
    const int cur = t & 1, nxt = cur ^ 1;
    short* Ac = As[cur][wmi];
    short* Bc = Bs[cur][wni >> 1];

    #pragma unroll
    for (int mt = 0; mt < 4; ++mt) {
      int r = mt * 16 + l15;
      #pragma unroll
      for (int ks = 0; ks < 2; ++ks)
        af[mt][ks] = *(const short8*)&Ac[r * 64 + ((((ks << 2) + quad) ^ (r & 7)) << 3)];
    }
    #pragma unroll
    for (int nt = 0; nt < 2; ++nt) {
      int r = brow0 + nt * 16 + l15;
      #pragma unroll
      for (int ks = 0; ks < 2; ++ks)
        bf0[nt][ks] = *(const short8*)&Bc[r * 64 + ((((ks << 2) + quad) ^ (r & 7)) << 3)];
    }
    if (t + 1 < NT) stage(As[nxt][1], srcA(t + 1, 1));
    asm volatile("s_barrier" ::: "memory");
    __builtin_amdgcn_sched_barrier(0);
    __builtin_amdgcn_s_setprio(1);
    #pragma unroll
    for (int mt = 0; mt < 4; ++mt)
      #pragma unroll
      for (int nt = 0; nt < 2; ++nt)
        #pragma unroll
        for (int ks = 0; ks < 2; ++ks)
          acc[mt][nt] = __builtin_amdgcn_mfma_f32_16x16x32_bf16(
              af[mt][ks], bf0[nt][ks], acc[mt][nt], 0, 0, 0);
    __builtin_amdgcn_s_setprio(0);
    __builtin_amdgcn_sched_barrier(0);
    asm volatile("s_barrier" ::: "memory");

    #pragma unroll
    for (int nt = 0; nt < 2; ++nt) {
      int r = brow0 + 32 + nt * 16 + l15;
      #pragma unroll
      for (int ks = 0; ks < 2; ++ks)
        bf1[nt][ks] = *(const short8*)&Bc[r * 64 + ((((ks << 2) + quad) ^ (r & 7)) << 3)];
    }
    asm volatile("s_barrier" ::: "memory");
    __builtin_amdgcn_sched_barrier(0);
    __builtin_amdgcn_s_setprio(1);
    #pragma unroll
    for (int mt = 0; mt < 4; ++mt)
      #pragma unroll
      for (int nt = 0; nt < 2; ++nt)
        #pragma unroll
        for (int ks = 0; ks < 2; ++ks)
          acc[mt][nt + 2] = __builtin_amdgcn_mfma_f32_16x16x32_bf16(
              af[mt][ks], bf1[nt][ks], acc[mt][nt + 2], 0, 0, 0);
    __builtin_amdgcn_s_setprio(0);
    __builtin_amdgcn_sched_barrier(0);
    asm volatile("s_barrier" ::: "memory");

    #pragma unroll
    for (int mt = 0; mt < 4; ++mt) {
      int r = 64 + mt * 16 + l15;
      #pragma unroll
      for (int ks = 0; ks < 2; ++ks)
        af[mt][ks] = *(const short8*)&Ac[r * 64 + ((((ks << 2) + quad) ^ (r & 7)) << 3)];
    }
    if (t + 2 < NT) stage(Bs[cur][0], srcB(t + 2, 0));
    asm volatile("s_barrier" ::: "memory");
    __builtin_amdgcn_sched_barrier(0);
    __builtin_amdgcn_s_setprio(1);
    #pragma unroll
    for (int mt = 0; mt < 4; ++mt)
      #pragma unroll
      for (int nt = 0; nt < 2; ++nt)
        #pragma unroll
        for (int ks = 0; ks < 2; ++ks)
          acc[mt + 4][nt + 2] = __builtin_amdgcn_mfma_f32_16x16x32_bf16(
              af[mt][ks], bf1[nt][ks], acc[mt + 4][nt + 2], 0, 0, 0);
    __builtin_amdgcn_s_setprio(0);
    __builtin_amdgcn_sched_barrier(0);
    asm volatile("s_barrier" ::: "memory");

    if (t + 2 < NT) {
      stage(Bs[cur][1], srcB(t + 2, 1));
      stage(As[cur][0], srcA(t + 2, 0));
    }
    __builtin_amdgcn_s_setprio(1);
    #pragma unroll
    for (int mt = 0; mt < 4; ++mt)
      #pragma unroll
      for (int nt = 0; nt < 2; ++nt)
        #pragma unroll
        for (int ks = 0; ks < 2; ++ks)
          acc[mt + 4][nt] = __builtin_amdgcn_mfma_f32_16x16x32_bf16(
              af[mt][ks], bf0[nt][ks], acc[mt + 4][nt], 0, 0, 0);
    __builtin_amdgcn_s_setprio(0);
    __builtin_amdgcn_sched_barrier(0);
    if (t < NT - 2) {
      asm volatile("s_waitcnt vmcnt(6)" ::: "memory");
      asm volatile("s_barrier" ::: "memory");
    } else if (t == NT - 2) {
      asm volatile("s_waitcnt vmcnt(0)" ::: "memory");
      asm volatile("s_barrier" ::: "memory");
    }
  }

  #pragma unroll
  for (int mt = 0; mt < 8; ++mt)
    #pragma unroll
    for (int nt = 0; nt < 4; ++nt)
      #pragma unroll
      for (int r = 0; r < 4; ++r) {
        int row = m0 + wmi * 128 + mt * 16 + quad * 4 + r;
        int col = n0 + wni * 64 + nt * 16 + l15;
        float v = acc[mt][nt][r] + bias[col];
        Cp[(size_t)row * N + col] = (short)f2bf(v);
      }
}

__global__ __launch_bounds__(256)
void proj_qr_kernel(const short* __restrict__ in_bf, const short* __restrict__ Wq_t,
                    const float* __restrict__ b_q, float* __restrict__ q_f32,
                    const short* __restrict__ pe_bf, const short* __restrict__ Wpos_t,
                    const float* __restrict__ b_pos, short* __restrict__ r_bf) {
  __shared__ short As[128 * 32];
  __shared__ short Bs[128 * 32];
  const int blk = blockIdx.x;
  if (blk < 256)
    gemm_body(As, Bs, in_bf, Wq_t, b_q, q_f32, 4096, 1024, 1024, 0,
              blk & 7, blk >> 3);
  else {
    int tb = blk - 256;
    gemm_body(As, Bs, pe_bf, Wpos_t, b_pos, r_bf, 1024, 1024, 1024, 1,
              tb & 7, tb >> 3);
  }
}

__global__ __launch_bounds__(256)
void out_gemm_kernel(const short* __restrict__ av_bf, const short* __restrict__ Wproj_t,
                     const float* __restrict__ b_proj, float* __restrict__ out) {
  __shared__ short As[128 * 32];
  __shared__ short Bs[128 * 32];
  gemm_body(As, Bs, av_bf, Wproj_t, b_proj, out, 4096, 1024, 1024, 0,
            blockIdx.x % 8, blockIdx.x / 8);
}

// ---------------------------------------------------------------------------
// K/R repack: fragment-friendly layouts so attn can load MFMA B-fragments
// directly from global with 128B row stride (R5's 32KB-stride L1 thrash fix).
//   Kf[(b*16+h)*1024 + key][d0..63]  <- kv_bf[(key*8+b)*2048 + h*64 + d]
//   Rf[h*1024 + pos][d0..63]         <- r_bf[pos*1024 + h*64 + d]
// Kf overwrites fi_bf (dead after kv8); Rf overwrites pe_bf (dead after qr).
// ---------------------------------------------------------------------------
__global__ __launch_bounds__(256)
void krt_kernel(const short* __restrict__ kvb, const short* __restrict__ rbf,
                short* __restrict__ Kf, short* __restrict__ Rf) {
  const int tid = threadIdx.x;
  const int t8 = tid & 7, tk = tid >> 3;
  const int d0 = t8 * 8;
  if (blockIdx.x < 512) {
    const int blk = blockIdx.x;
    const int bh = blk >> 2;                 // b*16 + h
    const int b = bh >> 4, h = bh & 15;
    const int kb = (blk & 3) * 256;
    #pragma unroll
    for (int pass = 0; pass < 8; ++pass) {
      int key = kb + pass * 32 + tk;
      short8 v = *(const short8*)&kvb[((size_t)key * 8 + b) * 2048 + h * 64 + d0];
      *(short8*)&Kf[((size_t)bh * 1024 + key) * 64 + d0] = v;
    }
  } else {
    const int blk = blockIdx.x - 512;
    const int h = blk >> 2;
    const int pb = (blk & 3) * 256;
    #pragma unroll
    for (int pass = 0; pass < 8; ++pass) {
      int pos = pb + pass * 32 + tk;
      short8 v = *(const short8*)&rbf[(size_t)pos * 1024 + h * 64 + d0];
      *(short8*)&Rf[((size_t)h * 1024 + pos) * 64 + d0] = v;
    }
  }
}

// ---------------------------------------------------------------------------
// Flash attention (R5 verified-correct structure): K and R MFMA B-fragments
// loaded DIRECTLY from fragment-friendly Kf/Rf (row stride 128B — a wave's
// 16 key-rows span 2KB contiguous, L1-resident, vs R5's 32KB-stride L1-set
// thrash). V keeps the Vt LDS transpose. LDS 43KB -> 3 blocks/CU.
// ---------------------------------------------------------------------------
__global__ __launch_bounds__(256, 3)
void attn_mfma_kernel(const float* __restrict__ qf, const short* __restrict__ kvb,
                      const short* __restrict__ Kf, const short* __restrict__ Rf,
                      const float* __restrict__ um, const float* __restrict__ vm,
                      short* __restrict__ avb) {
  const int h = blockIdx.x, qt = blockIdx.y, b = blockIdx.z;
  const int tid = threadIdx.x;
  const int w = tid >> 6, lane = tid & 63, l15 = lane & 15, quad = lane >> 4;
  const float SCL2E = 0.125f * 1.44269504089f;   // fold scale + log2(e) into q

  __shared__ unsigned int Vt[2][64 * 32];  // [buf][d][key-pair], chunk-swizzled
  __shared__ short Pb[2][64 * 69];         // Ptilde chunks (bf16), stride 69
  __shared__ short Pt[4][16 * 72];         // per-wave P (bf16)

  const int jtmax = qt + 8;
  const int dfrag = quad * 8;
  const short* Kh = Kf + ((size_t)(b * 16 + h) * 1024) * 64;  // [key][64]
  const short* Rh = Rf + ((size_t)h * 1024) * 64;             // [pos][64]

  // ---- Q fragments (A-layout), u/v pre-added, pre-scaled, bf16 ----
  short8 qu_[2], qv_[2];
  {
    int qrow = qt * 64 + w * 16 + l15;
    size_t gbase = ((size_t)qrow * BSZ + b) * 1024 + h * 64;
    #pragma unroll
    for (int ks = 0; ks < 2; ++ks) {
      int d0 = ks * 32 + quad * 8;
      float qa[8], ua[8], va[8];
      *(float4*)&qa[0] = *(const float4*)&qf[gbase + d0];
      *(float4*)&qa[4] = *(const float4*)&qf[gbase + d0 + 4];
      *(float4*)&ua[0] = *(const float4*)&um[h * 64 + d0];
      *(float4*)&ua[4] = *(const float4*)&um[h * 64 + d0 + 4];
      *(float4*)&va[0] = *(const float4*)&vm[h * 64 + d0];
      *(float4*)&va[4] = *(const float4*)&vm[h * 64 + d0 + 4];
      #pragma unroll
      for (int j = 0; j < 8; ++j) {
        qu_[ks][j] = f2bf((qa[j] + ua[j]) * SCL2E);
        qv_[ks][j] = f2bf((qa[j] + va[j]) * SCL2E);
      }
    }
  }

  // ---- V staging (global -> regs -> swizzled Vt LDS) ----
  const int dc = tid & 7, kp = tid >> 3;
  auto loadV = [&](int jt, short8* va, short8* vb) {
    size_t g0 = ((size_t)(jt * 64 + kp * 2) * BSZ + b) * 2048 + 1024 + h * 64 + dc * 8;
    *va = *(const short8*)&kvb[g0];
    *vb = *(const short8*)&kvb[g0 + 2048 * BSZ];
  };
  auto packV = [&](int buf, short8 va, short8 vb) {
    #pragma unroll
    for (int i = 0; i < 8; ++i) {
      int d = dc * 8 + i;
      int swz = (i ^ dc) & 7;
      Vt[buf][d * 32 + (((kp >> 2) ^ swz) * 4) + (kp & 3)] =
          (unsigned int)(unsigned short)va[i] |
          ((unsigned int)(unsigned short)vb[i] << 16);
    }
  };

  // ---- position chunk: R B-frags direct from Rf ----
  auto compute_chunk = [&](int buf, int rowbase) {
    #pragma unroll
    for (int nt = 0; nt < 4; ++nt) {
      floatx4 a = (floatx4){0.f, 0.f, 0.f, 0.f};
      #pragma unroll
      for (int ks = 0; ks < 2; ++ks) {
        short8 bfr = *(const short8*)
            &Rh[(size_t)(rowbase + nt * 16 + l15) * 64 + ks * 32 + dfrag];
        a = __builtin_amdgcn_mfma_f32_16x16x32_bf16(qv_[ks], bfr, a, 0, 0, 0);
      }
      #pragma unroll
      for (int r = 0; r < 4; ++r)
        Pb[buf][(w * 16 + quad * 4 + r) * 69 + nt * 16 + l15] = (short)f2bf(a[r]);
    }
  };

  // ---- prologue ----
  short8 vra, vrb;
  loadV(0, &vra, &vrb);
  packV(0, vra, vrb);
  compute_chunk(1, 448 - qt * 64);   // Pb is wave-local: no barrier needed
  __syncthreads();                    // Vt[0] visible to all waves

  floatx4 O[4], O5;
  O5 = (floatx4){0.f, 0.f, 0.f, 0.f};
  #pragma unroll
  for (int nt = 0; nt < 4; ++nt) O[nt] = (floatx4){0.f, 0.f, 0.f, 0.f};
  short8 ones;
  #pragma unroll
  for (int j = 0; j < 8; ++j) ones[j] = (short)0x3F80;  // bf16 1.0

  for (int jt = 0; jt <= jtmax; ++jt) {
    const int cur = jt & 1, nxt = cur ^ 1;

    if (jt < jtmax) {
      loadV(jt + 1, &vra, &vrb);
      compute_chunk(cur, 512 - qt * 64 + 64 * jt);   // Pb[cur] (wave-local)
    }

    // ---- content scores: K B-frags direct from Kf ----
    floatx4 S[4];
    #pragma unroll
    for (int nt = 0; nt < 4; ++nt) {
      S[nt] = (floatx4){0.f, 0.f, 0.f, 0.f};
      #pragma unroll
      for (int ks = 0; ks < 2; ++ks) {
        short8 bfr = *(const short8*)
            &Kh[(size_t)(jt * 64 + nt * 16 + l15) * 64 + ks * 32 + dfrag];
        S[nt] = __builtin_amdgcn_mfma_f32_16x16x32_bf16(qu_[ks], bfr, S[nt], 0, 0, 0);
      }
    }

    // ---- rel-shift gather + mask + exp2 (Pb wave-local) ----
    #pragma unroll
    for (int nt = 0; nt < 4; ++nt) {
      #pragma unroll
      for (int r = 0; r < 4; ++r) {
        int il = w * 16 + quad * 4 + r;
        int jl = nt * 16 + l15;
        int rel = jl - il + 63;
        float pos = (rel >= 64) ? bf2f((unsigned short)Pb[cur][il * 69 + rel - 64])
                                : bf2f((unsigned short)Pb[nxt][il * 69 + rel]);
        float z = S[nt][r] + pos;
        if (jt == jtmax && jl > il) z = -1e30f;
        S[nt][r] = __builtin_amdgcn_exp2f(z);
      }
    }

    // ---- P -> LDS (wave-local), read back as A-fragments ----
    #pragma unroll
    for (int nt = 0; nt < 4; ++nt)
      #pragma unroll
      for (int r = 0; r < 4; ++r)
        Pt[w][(quad * 4 + r) * 72 + nt * 16 + l15] = (short)f2bf(S[nt][r]);

    short8 pf[2];
    #pragma unroll
    for (int ks = 0; ks < 2; ++ks)
      pf[ks] = *(const short8*)&Pt[w][l15 * 72 + ks * 32 + quad * 8];

    // ---- row-sums via ones-MFMA ----
    #pragma unroll
    for (int ks = 0; ks < 2; ++ks)
      O5 = __builtin_amdgcn_mfma_f32_16x16x32_bf16(pf[ks], ones, O5, 0, 0, 0);

    // ---- O += P @ V ----
    #pragma unroll
    for (int ntd = 0; ntd < 4; ++ntd) {
      int d = ntd * 16 + l15;
      int swv = (d ^ (d >> 3)) & 7;
      #pragma unroll
      for (int ks = 0; ks < 2; ++ks) {
        short8 vfr = *(const short8*)&Vt[cur][d * 32 + (((ks * 4 + quad) ^ swv) * 4)];
        O[ntd] = __builtin_amdgcn_mfma_f32_16x16x32_bf16(pf[ks], vfr, O[ntd], 0, 0, 0);
      }
    }

    if (jt < jtmax) packV(nxt, vra, vrb);

    __syncthreads();   // Vt[nxt] complete before next iter's PV reads it
  }

  // ---- epilogue: normalize by O5 row-sums, write ----
  #pragma unroll
  for (int r = 0; r < 4; ++r) {
    float inv = 1.f / O5[r];
    int qrow = qt * 64 + w * 16 + quad * 4 + r;
    size_t gb = ((size_t)qrow * BSZ + b) * 1024 + h * 64;
    #pragma unroll
    for (int ntd = 0; ntd < 4; ++ntd)
      avb[gb + ntd * 16 + l15] = (short)f2bf(O[ntd][r] * inv);
  }
}

// ---------------------------------------------------------------------------
extern "C" void kernel_launch(void* const* d_in, const int* in_sizes, int n_in,
                              void* d_out, int out_size, void* d_ws, size_t ws_size,
                              hipStream_t stream) {
  const float* inputs  = (const float*)d_in[0];
  const float* pos_emb = (const float*)d_in[1];
  const float* full_in = (const float*)d_in[2];
  const float* u       = (const float*)d_in[3];
  const float* v       = (const float*)d_in[4];
  const float* W_kv    = (const float*)d_in[6];
  const float* b_kv    = (const float*)d_in[7];
  const float* W_q     = (const float*)d_in[8];
  const float* b_q     = (const float*)d_in[9];
  const float* W_pos   = (const float*)d_in[10];
  const float* b_pos   = (const float*)d_in[11];
  const float* W_proj  = (const float*)d_in[12];
  const float* b_proj  = (const float*)d_in[13];
  float* out = (float*)d_out;

  char* ws = (char*)d_ws;
  short* fi_bf   = (short*)(ws + 0);          // 8192x1024 bf16  16 MB (later: Kf)
  short* in_bf   = (short*)(ws + 16777216);   // 4096x1024 bf16   8 MB
  short* pe_bf   = (short*)(ws + 25165824);   // 1024x1024 bf16   2 MB (later: Rf)
  short* Wkv_t   = (short*)(ws + 27262976);   // 2048x1024 bf16   4 MB
  short* Wq_t    = (short*)(ws + 31457280);   // 1024x1024 bf16   2 MB
  short* Wpos_t  = (short*)(ws + 33554432);   // 1024x1024 bf16   2 MB
  short* Wproj_t = (short*)(ws + 35651584);   // 1024x1024 bf16   2 MB
  short* kv_bf   = (short*)(ws + 37748736);   // 8192x2048 bf16  32 MB
  float* q_f32   = (float*)(ws + 71303168);   // 4096x1024 fp32  16 MB
  short* r_bf    = (short*)(ws + 88080384);   // 1024x1024 bf16   2 MB
  short* av_bf   = (short*)(ws + 90177536);   // 4096x1024 bf16   8 MB
  short* Kf      = fi_bf;                     // fi_bf dead after proj_kv8
  short* Rf      = pe_bf;                     // pe_bf dead after proj_qr

  prep_kernel<<<7936, 256, 0, stream>>>(full_in, fi_bf, inputs, in_bf,
                                        pos_emb, pe_bf, W_kv, Wkv_t, W_q, Wq_t,
                                        W_pos, Wpos_t, W_proj, Wproj_t);

  proj_kv8_kernel<<<256, 512, 0, stream>>>(fi_bf, Wkv_t, b_kv, kv_bf);

  proj_qr_kernel<<<320, 256, 0, stream>>>(in_bf, Wq_t, b_q, q_f32,
                                          pe_bf, Wpos_t, b_pos, r_bf);

  krt_kernel<<<576, 256, 0, stream>>>(kv_bf, r_bf, Kf, Rf);

  attn_mfma_kernel<<<dim3(NH, 8, BSZ), 256, 0, stream>>>(q_f32, kv_bf, Kf, Rf,
                                                         u, v, av_bf);

  out_gemm_kernel<<<256, 256, 0, stream>>>(av_bf, Wproj_t, b_proj, out);
}

// Round 9
// 285.343 us; speedup vs baseline: 1.2703x; 1.2703x over previous
//
#include <hip/hip_runtime.h>

#define CUR 512
#define FULLS 1024
#define BSZ 8
#define DIMM 1024
#define NH 16
#define HD 64

typedef __attribute__((ext_vector_type(8))) short short8;
typedef __attribute__((ext_vector_type(4))) float floatx4;

__device__ __forceinline__ unsigned short f2bf(float x) {
  unsigned int u = __float_as_uint(x);
  unsigned int r = (u + 0x7fffu + ((u >> 16) & 1u)) >> 16;
  return (unsigned short)r;
}
__device__ __forceinline__ float bf2f(unsigned short h) {
  return __uint_as_float(((unsigned int)h) << 16);
}

__device__ __forceinline__ void async16(void* lds, const void* g) {
  __builtin_amdgcn_global_load_lds(
      (const __attribute__((address_space(1))) unsigned int*)g,
      (__attribute__((address_space(3))) unsigned int*)lds, 16, 0, 0);
}

// ---------------------------------------------------------------------------
// Fused prep: all fp32->bf16 casts + weight transpose-casts in ONE launch.
// ---------------------------------------------------------------------------
__global__ __launch_bounds__(256)
void prep_kernel(const float* __restrict__ fi, short* __restrict__ fi_bf,
                 const float* __restrict__ inp, short* __restrict__ in_bf,
                 const float* __restrict__ pe, short* __restrict__ pe_bf,
                 const float* __restrict__ Wkv, short* __restrict__ Wkv_t,
                 const float* __restrict__ Wq, short* __restrict__ Wq_t,
                 const float* __restrict__ Wpos, short* __restrict__ Wpos_t,
                 const float* __restrict__ Wproj, short* __restrict__ Wproj_t) {
  __shared__ float t[64][65];
  const int blk = blockIdx.x;
  const int tid = threadIdx.x;
  if (blk < 6656) {
    const float* x; short* y; int base;
    if (blk < 4096)      { x = fi;  y = fi_bf; base = blk; }
    else if (blk < 6144) { x = inp; y = in_bf; base = blk - 4096; }
    else                 { x = pe;  y = pe_bf; base = blk - 6144; }
    int i = (base * 256 + tid) * 8;
    float a[8];
    *(float4*)&a[0] = *(const float4*)&x[i];
    *(float4*)&a[4] = *(const float4*)&x[i + 4];
    short8 o;
    #pragma unroll
    for (int j = 0; j < 8; ++j) o[j] = f2bf(a[j]);
    *(short8*)&y[i] = o;
    return;
  }
  const float* W; short* Wt; int N, t2;
  if (blk < 7168)      { W = Wkv;   Wt = Wkv_t;   N = 2048; t2 = blk - 6656; }
  else if (blk < 7424) { W = Wq;    Wt = Wq_t;    N = 1024; t2 = blk - 7168; }
  else if (blk < 7680) { W = Wpos;  Wt = Wpos_t;  N = 1024; t2 = blk - 7424; }
  else                 { W = Wproj; Wt = Wproj_t; N = 1024; t2 = blk - 7680; }
  const int K = 1024;
  const int nx = N / 64;
  const int n0 = (t2 % nx) * 64, k0 = (t2 / nx) * 64;
  #pragma unroll
  for (int r = 0; r < 4; ++r) {
    int f = tid + r * 256;
    int row = f >> 4, c = (f & 15) * 4;
    float4 v = *(const float4*)&W[(size_t)(k0 + row) * N + n0 + c];
    t[c + 0][row] = v.x; t[c + 1][row] = v.y;
    t[c + 2][row] = v.z; t[c + 3][row] = v.w;
  }
  __syncthreads();
  #pragma unroll
  for (int r = 0; r < 2; ++r) {
    int f = tid + r * 256;
    int row = f >> 3, c = (f & 7) * 8;
    short8 o;
    #pragma unroll
    for (int j = 0; j < 8; ++j) o[j] = f2bf(t[row][c + j]);
    *(short8*)&Wt[(size_t)(n0 + row) * K + k0 + c] = o;
  }
}

// ---------------------------------------------------------------------------
// bf16 MFMA GEMM body (m97 structure, 128x128 tile) — q/r/out GEMMs.
// ---------------------------------------------------------------------------
__device__ __forceinline__
void gemm_body(short* As, short* Bs,
               const short* __restrict__ A, const short* __restrict__ Bt,
               const float* __restrict__ bias, void* __restrict__ Cp,
               int M, int N, int K, int out_bf16, int bx, int by) {
  const int tid = threadIdx.x;
  const int w = tid >> 6, lane = tid & 63, l15 = lane & 15, quad = lane >> 4;
  const int m0 = by * 128, n0 = bx * 128;
  const int wm = (w & 1) * 64, wn = (w >> 1) * 64;

  floatx4 acc[4][4];
  #pragma unroll
  for (int i = 0; i < 4; ++i)
    #pragma unroll
    for (int j = 0; j < 4; ++j) acc[i][j] = (floatx4){0.f, 0.f, 0.f, 0.f};

  for (int k0 = 0; k0 < K; k0 += 32) {
    __syncthreads();
    #pragma unroll
    for (int rnd = 0; rnd < 2; ++rnd) {
      int fb = rnd * 256 + w * 64;
      int f = fb + lane;
      int row = f >> 2, c = f & 3;
      int cs = (c ^ (row & 3)) * 8;
      async16(As + fb * 8, &A[(size_t)(m0 + row) * K + k0 + cs]);
      async16(Bs + fb * 8, &Bt[(size_t)(n0 + row) * K + k0 + cs]);
    }
    __syncthreads();
    short8 af[4], bf[4];
    #pragma unroll
    for (int t = 0; t < 4; ++t) {
      int swz = ((quad ^ (l15 & 3)) * 8);
      af[t] = *(const short8*)&As[(wm + t * 16 + l15) * 32 + swz];
      bf[t] = *(const short8*)&Bs[(wn + t * 16 + l15) * 32 + swz];
    }
    #pragma unroll
    for (int mt = 0; mt < 4; ++mt)
      #pragma unroll
      for (int nt = 0; nt < 4; ++nt)
        acc[mt][nt] = __builtin_amdgcn_mfma_f32_16x16x32_bf16(
            af[mt], bf[nt], acc[mt][nt], 0, 0, 0);
  }

  #pragma unroll
  for (int mt = 0; mt < 4; ++mt)
    #pragma unroll
    for (int nt = 0; nt < 4; ++nt)
      #pragma unroll
      for (int r = 0; r < 4; ++r) {
        int row = m0 + wm + mt * 16 + quad * 4 + r;
        int col = n0 + wn + nt * 16 + l15;
        float v = acc[mt][nt][r] + bias[col];
        if (out_bf16) ((short*)Cp)[(size_t)row * N + col] = (short)f2bf(v);
        else          ((float*)Cp)[(size_t)row * N + col] = v;
      }
}

// ---------------------------------------------------------------------------
// kv-only 256x256-tile 8-phase bf16 GEMM. 256 blocks = one dispatch round.
// ---------------------------------------------------------------------------
__global__ __launch_bounds__(512, 2)
void proj_kv8_kernel(const short* __restrict__ A, const short* __restrict__ Bt,
                     const float* __restrict__ bias, short* __restrict__ Cp) {
  __shared__ __align__(16) short As[2][2][128 * 64];
  __shared__ __align__(16) short Bs[2][2][128 * 64];

  const int blk = blockIdx.x;
  const int xcd = blk & 7, l = blk >> 3;
  const int bx = (xcd & 1) * 4 + (l & 3);
  const int by = (xcd >> 1) * 8 + (l >> 2);
  const int N = 2048;

  const int tid = threadIdx.x;
  const int w = tid >> 6, lane = tid & 63, l15 = lane & 15, quad = lane >> 4;
  const int wmi = w >> 2, wni = w & 3;
  const int m0 = by * 256, n0 = bx * 256;
  const int brow0 = (wni & 1) * 64;
  constexpr int NT = 16;

  auto stage = [&](short* dst, const short* src) {
    #pragma unroll
    for (int rnd = 0; rnd < 2; ++rnd) {
      int fb = rnd * 512 + w * 64;
      int f = fb + lane;
      int row = f >> 3, c = f & 7;
      async16(dst + fb * 8, src + (size_t)row * 1024 + ((c ^ (row & 7)) << 3));
    }
  };
  auto srcA = [&](int tt, int h) { return A + ((size_t)(m0 + h * 128)) * 1024 + tt * 64; };
  auto srcB = [&](int tt, int h) { return Bt + ((size_t)(n0 + h * 128)) * 1024 + tt * 64; };

  stage(As[0][0], srcA(0, 0));
  stage(Bs[0][0], srcB(0, 0));
  stage(Bs[0][1], srcB(0, 1));
  stage(As[0][1], srcA(0, 1));
  stage(As[1][0], srcA(1, 0));
  stage(Bs[1][0], srcB(1, 0));
  stage(Bs[1][1], srcB(1, 1));
  asm volatile("s_waitcnt vmcnt(6)" ::: "memory");
  asm volatile("s_barrier" ::: "memory");

  floatx4 acc[8][4];
  #pragma unroll
  for (int i = 0; i < 8; ++i)
    #pragma unroll
    for (int j = 0; j < 4; ++j) acc[i][j] = (floatx4){0.f, 0.f, 0.f, 0.f};

  short8 af[4][2], bf0[2][2], bf1[2][2];

  #pragma unroll 1
  for (int t = 0; t < NT; ++t) {
    const int cur = t & 1, nxt = cur ^ 1;
    short* Ac = As[cur][wmi];
    short* Bc = Bs[cur][wni >> 1];

    #pragma unroll
    for (int mt = 0; mt < 4; ++mt) {
      int r = mt * 16 + l15;
      #pragma unroll
      for (int ks = 0; ks < 2; ++ks)
        af[mt][ks] = *(const short8*)&Ac[r * 64 + ((((ks << 2) + quad) ^ (r & 7)) << 3)];
    }
    #pragma unroll
    for (int nt = 0; nt < 2; ++nt) {
      int r = brow0 + nt * 16 + l15;
      #pragma unroll
      for (int ks = 0; ks < 2; ++ks)
        bf0[nt][ks] = *(const short8*)&Bc[r * 64 + ((((ks << 2) + quad) ^ (r & 7)) << 3)];
    }
    if (t + 1 < NT) stage(As[nxt][1], srcA(t + 1, 1));
    asm volatile("s_barrier" ::: "memory");
    __builtin_amdgcn_sched_barrier(0);
    __builtin_amdgcn_s_setprio(1);
    #pragma unroll
    for (int mt = 0; mt < 4; ++mt)
      #pragma unroll
      for (int nt = 0; nt < 2; ++nt)
        #pragma unroll
        for (int ks = 0; ks < 2; ++ks)
          acc[mt][nt] = __builtin_amdgcn_mfma_f32_16x16x32_bf16(
              af[mt][ks], bf0[nt][ks], acc[mt][nt], 0, 0, 0);
    __builtin_amdgcn_s_setprio(0);
    __builtin_amdgcn_sched_barrier(0);
    asm volatile("s_barrier" ::: "memory");

    #pragma unroll
    for (int nt = 0; nt < 2; ++nt) {
      int r = brow0 + 32 + nt * 16 + l15;
      #pragma unroll
      for (int ks = 0; ks < 2; ++ks)
        bf1[nt][ks] = *(const short8*)&Bc[r * 64 + ((((ks << 2) + quad) ^ (r & 7)) << 3)];
    }
    asm volatile("s_barrier" ::: "memory");
    __builtin_amdgcn_sched_barrier(0);
    __builtin_amdgcn_s_setprio(1);
    #pragma unroll
    for (int mt = 0; mt < 4; ++mt)
      #pragma unroll
      for (int nt = 0; nt < 2; ++nt)
        #pragma unroll
        for (int ks = 0; ks < 2; ++ks)
          acc[mt][nt + 2] = __builtin_amdgcn_mfma_f32_16x16x32_bf16(
              af[mt][ks], bf1[nt][ks], acc[mt][nt + 2], 0, 0, 0);
    __builtin_amdgcn_s_setprio(0);
    __builtin_amdgcn_sched_barrier(0);
    asm volatile("s_barrier" ::: "memory");

    #pragma unroll
    for (int mt = 0; mt < 4; ++mt) {
      int r = 64 + mt * 16 + l15;
      #pragma unroll
      for (int ks = 0; ks < 2; ++ks)
        af[mt][ks] = *(const short8*)&Ac[r * 64 + ((((ks << 2) + quad) ^ (r & 7)) << 3)];
    }
    if (t + 2 < NT) stage(Bs[cur][0], srcB(t + 2, 0));
    asm volatile("s_barrier" ::: "memory");
    __builtin_amdgcn_sched_barrier(0);
    __builtin_amdgcn_s_setprio(1);
    #pragma unroll
    for (int mt = 0; mt < 4; ++mt)
      #pragma unroll
      for (int nt = 0; nt < 2; ++nt)
        #pragma unroll
        for (int ks = 0; ks < 2; ++ks)
          acc[mt + 4][nt + 2] = __builtin_amdgcn_mfma_f32_16x16x32_bf16(
              af[mt][ks], bf1[nt][ks], acc[mt + 4][nt + 2], 0, 0, 0);
    __builtin_amdgcn_s_setprio(0);
    __builtin_amdgcn_sched_barrier(0);
    asm volatile("s_barrier" ::: "memory");

    if (t + 2 < NT) {
      stage(Bs[cur][1], srcB(t + 2, 1));
      stage(As[cur][0], srcA(t + 2, 0));
    }
    __builtin_amdgcn_s_setprio(1);
    #pragma unroll
    for (int mt = 0; mt < 4; ++mt)
      #pragma unroll
      for (int nt = 0; nt < 2; ++nt)
        #pragma unroll
        for (int ks = 0; ks < 2; ++ks)
          acc[mt + 4][nt] = __builtin_amdgcn_mfma_f32_16x16x32_bf16(
              af[mt][ks], bf0[nt][ks], acc[mt + 4][nt], 0, 0, 0);
    __builtin_amdgcn_s_setprio(0);
    __builtin_amdgcn_sched_barrier(0);
    if (t < NT - 2) {
      asm volatile("s_waitcnt vmcnt(6)" ::: "memory");
      asm volatile("s_barrier" ::: "memory");
    } else if (t == NT - 2) {
      asm volatile("s_waitcnt vmcnt(0)" ::: "memory");
      asm volatile("s_barrier" ::: "memory");
    }
  }

  #pragma unroll
  for (int mt = 0; mt < 8; ++mt)
    #pragma unroll
    for (int nt = 0; nt < 4; ++nt)
      #pragma unroll
      for (int r = 0; r < 4; ++r) {
        int row = m0 + wmi * 128 + mt * 16 + quad * 4 + r;
        int col = n0 + wni * 64 + nt * 16 + l15;
        float v = acc[mt][nt][r] + bias[col];
        Cp[(size_t)row * N + col] = (short)f2bf(v);
      }
}

__global__ __launch_bounds__(256)
void proj_qr_kernel(const short* __restrict__ in_bf, const short* __restrict__ Wq_t,
                    const float* __restrict__ b_q, float* __restrict__ q_f32,
                    const short* __restrict__ pe_bf, const short* __restrict__ Wpos_t,
                    const float* __restrict__ b_pos, short* __restrict__ r_bf) {
  __shared__ short As[128 * 32];
  __shared__ short Bs[128 * 32];
  const int blk = blockIdx.x;
  if (blk < 256)
    gemm_body(As, Bs, in_bf, Wq_t, b_q, q_f32, 4096, 1024, 1024, 0,
              blk & 7, blk >> 3);
  else {
    int tb = blk - 256;
    gemm_body(As, Bs, pe_bf, Wpos_t, b_pos, r_bf, 1024, 1024, 1024, 1,
              tb & 7, tb >> 3);
  }
}

__global__ __launch_bounds__(256)
void out_gemm_kernel(const short* __restrict__ av_bf, const short* __restrict__ Wproj_t,
                     const float* __restrict__ b_proj, float* __restrict__ out) {
  __shared__ short As[128 * 32];
  __shared__ short Bs[128 * 32];
  gemm_body(As, Bs, av_bf, Wproj_t, b_proj, out, 4096, 1024, 1024, 0,
            blockIdx.x % 8, blockIdx.x / 8);
}

// ---------------------------------------------------------------------------
// Pipelined MFMA flash attention (R4 proven structure, wave-local P):
//  - K/R staged via async16 (global_load_lds) one iteration ahead — zero
//    VGPR cost, LDS-fed MFMA operands (direct global feeds serialize; R5-R8).
//  - post-prologue __syncthreads (closes latent Rs[0] WAR window)
//  - row-sums via ones-MFMA into O5
// ---------------------------------------------------------------------------
__global__ __launch_bounds__(256, 2)
void attn_mfma_kernel(const float* __restrict__ qf, const short* __restrict__ kvb,
                      const short* __restrict__ rb, const float* __restrict__ um,
                      const float* __restrict__ vm, short* __restrict__ avb) {
  const int h = blockIdx.x, qt = blockIdx.y, b = blockIdx.z;
  const int tid = threadIdx.x;
  const int w = tid >> 6, lane = tid & 63, l15 = lane & 15, quad = lane >> 4;
  const float SCL2E = 0.125f * 1.44269504089f;   // fold scale + log2(e) into q

  __shared__ short Ks[2][64 * 64];         // [buf][row][chunk-swizzled d]
  __shared__ short Rs[2][64 * 64];         // [buf][row][chunk-swizzled d]
  __shared__ unsigned int Vt[2][64 * 32];  // [buf][d][key-pair], chunk-swizzled
  __shared__ short Pb[2][64 * 69];         // Ptilde chunks (bf16), stride 69
  __shared__ short Pt[4][16 * 72];         // per-wave P (bf16)

  const int jtmax = qt + 8;

  // ---- Q fragments (A-layout), u/v pre-added, pre-scaled, bf16 ----
  short8 qu_[2], qv_[2];
  {
    int qrow = qt * 64 + w * 16 + l15;
    size_t gbase = ((size_t)qrow * BSZ + b) * 1024 + h * 64;
    #pragma unroll
    for (int ks = 0; ks < 2; ++ks) {
      int d0 = ks * 32 + quad * 8;
      float qa[8], ua[8], va[8];
      *(float4*)&qa[0] = *(const float4*)&qf[gbase + d0];
      *(float4*)&qa[4] = *(const float4*)&qf[gbase + d0 + 4];
      *(float4*)&ua[0] = *(const float4*)&um[h * 64 + d0];
      *(float4*)&ua[4] = *(const float4*)&um[h * 64 + d0 + 4];
      *(float4*)&va[0] = *(const float4*)&vm[h * 64 + d0];
      *(float4*)&va[4] = *(const float4*)&vm[h * 64 + d0 + 4];
      #pragma unroll
      for (int j = 0; j < 8; ++j) {
        qu_[ks][j] = f2bf((qa[j] + ua[j]) * SCL2E);
        qv_[ks][j] = f2bf((qa[j] + va[j]) * SCL2E);
      }
    }
  }

  // ---- staging helpers (async16: dest lane-contiguous, source swizzled) ----
  auto stage_K = [&](int buf, int jt) {
    #pragma unroll
    for (int rnd = 0; rnd < 2; ++rnd) {
      int fb = rnd * 256 + w * 64;
      int f = fb + lane;
      int row = f >> 3, c = f & 7;
      int cs = (c ^ (row & 7)) * 8;
      async16(&Ks[buf][fb * 8],
              &kvb[((size_t)(jt * 64 + row) * BSZ + b) * 2048 + h * 64 + cs]);
    }
  };
  auto stage_R = [&](int buf, int p0) {
    #pragma unroll
    for (int rnd = 0; rnd < 2; ++rnd) {
      int fb = rnd * 256 + w * 64;
      int f = fb + lane;
      int row = f >> 3, c = f & 7;
      int cs = (c ^ (row & 7)) * 8;
      async16(&Rs[buf][fb * 8], &rb[(size_t)(p0 + row) * 1024 + h * 64 + cs]);
    }
  };
  const int dc = tid & 7, kp = tid >> 3;
  auto loadV = [&](int jt, short8* va, short8* vb) {
    size_t g0 = ((size_t)(jt * 64 + kp * 2) * BSZ + b) * 2048 + 1024 + h * 64 + dc * 8;
    *va = *(const short8*)&kvb[g0];
    *vb = *(const short8*)&kvb[g0 + 2048 * BSZ];
  };
  auto packV = [&](int buf, short8 va, short8 vb) {
    #pragma unroll
    for (int i = 0; i < 8; ++i) {
      int d = dc * 8 + i;
      int swz = (i ^ dc) & 7;
      Vt[buf][d * 32 + (((kp >> 2) ^ swz) * 4) + (kp & 3)] =
          (unsigned int)(unsigned short)va[i] |
          ((unsigned int)(unsigned short)vb[i] << 16);
    }
  };
  auto compute_chunk = [&](int buf, int rbuf) {
    #pragma unroll
    for (int nt = 0; nt < 4; ++nt) {
      floatx4 a = (floatx4){0.f, 0.f, 0.f, 0.f};
      #pragma unroll
      for (int ks = 0; ks < 2; ++ks) {
        short8 bfr = *(const short8*)
            &Rs[rbuf][(nt * 16 + l15) * 64 + (((ks * 4 + quad) ^ (l15 & 7)) * 8)];
        a = __builtin_amdgcn_mfma_f32_16x16x32_bf16(qv_[ks], bfr, a, 0, 0, 0);
      }
      #pragma unroll
      for (int r = 0; r < 4; ++r)
        Pb[buf][(w * 16 + quad * 4 + r) * 69 + nt * 16 + l15] = (short)f2bf(a[r]);
    }
  };

  // ---- prologue ----
  stage_K(0, 0);
  stage_R(0, 448 - qt * 64);
  stage_R(1, 512 - qt * 64);
  short8 vra, vrb;
  loadV(0, &vra, &vrb);
  packV(0, vra, vrb);
  __syncthreads();

  compute_chunk(1, 0);
  // Latent-race fix: jt=0's stage_R(0,...) async-writes Rs[0]; a lagging wave
  // may still be reading Rs[0] above. Separate with a barrier.
  __syncthreads();

  floatx4 O[4], O5;
  O5 = (floatx4){0.f, 0.f, 0.f, 0.f};
  #pragma unroll
  for (int nt = 0; nt < 4; ++nt) O[nt] = (floatx4){0.f, 0.f, 0.f, 0.f};
  short8 ones;
  #pragma unroll
  for (int j = 0; j < 8; ++j) ones[j] = (short)0x3F80;  // bf16 1.0

  for (int jt = 0; jt <= jtmax; ++jt) {
    const int cur = jt & 1, nxt = cur ^ 1;

    if (jt < jtmax) {
      stage_K(nxt, jt + 1);
      loadV(jt + 1, &vra, &vrb);
    }
    if (jt + 1 < jtmax) stage_R(cur, 512 + 64 * (jt + 1 - qt));

    if (jt < jtmax) compute_chunk(cur, nxt);

    // ---- content scores (already in log2 domain via pre-scaled q) ----
    floatx4 S[4];
    #pragma unroll
    for (int nt = 0; nt < 4; ++nt) {
      S[nt] = (floatx4){0.f, 0.f, 0.f, 0.f};
      #pragma unroll
      for (int ks = 0; ks < 2; ++ks) {
        short8 bfr = *(const short8*)
            &Ks[cur][(nt * 16 + l15) * 64 + (((ks * 4 + quad) ^ (l15 & 7)) * 8)];
        S[nt] = __builtin_amdgcn_mfma_f32_16x16x32_bf16(qu_[ks], bfr, S[nt], 0, 0, 0);
      }
    }

    // ---- rel-shift gather + mask + exp2 (no max, no rescale) ----
    #pragma unroll
    for (int nt = 0; nt < 4; ++nt) {
      #pragma unroll
      for (int r = 0; r < 4; ++r) {
        int il = w * 16 + quad * 4 + r;
        int jl = nt * 16 + l15;
        int rel = jl - il + 63;
        float pos = (rel >= 64) ? bf2f((unsigned short)Pb[cur][il * 69 + rel - 64])
                                : bf2f((unsigned short)Pb[nxt][il * 69 + rel]);
        float z = S[nt][r] + pos;
        if (jt == jtmax && jl > il) z = -1e30f;
        S[nt][r] = __builtin_amdgcn_exp2f(z);
      }
    }

    // ---- P -> LDS (wave-local), read back as A-fragments ----
    #pragma unroll
    for (int nt = 0; nt < 4; ++nt)
      #pragma unroll
      for (int r = 0; r < 4; ++r)
        Pt[w][(quad * 4 + r) * 72 + nt * 16 + l15] = (short)f2bf(S[nt][r]);

    short8 pf[2];
    #pragma unroll
    for (int ks = 0; ks < 2; ++ks)
      pf[ks] = *(const short8*)&Pt[w][l15 * 72 + ks * 32 + quad * 8];

    // ---- row-sums via ones-MFMA: O5[r] += sum_k P[quad*4+r][k] ----
    #pragma unroll
    for (int ks = 0; ks < 2; ++ks)
      O5 = __builtin_amdgcn_mfma_f32_16x16x32_bf16(pf[ks], ones, O5, 0, 0, 0);

    // ---- O += P @ V ----
    #pragma unroll
    for (int ntd = 0; ntd < 4; ++ntd) {
      int d = ntd * 16 + l15;
      int swv = (d ^ (d >> 3)) & 7;
      #pragma unroll
      for (int ks = 0; ks < 2; ++ks) {
        short8 vfr = *(const short8*)&Vt[cur][d * 32 + (((ks * 4 + quad) ^ swv) * 4)];
        O[ntd] = __builtin_amdgcn_mfma_f32_16x16x32_bf16(pf[ks], vfr, O[ntd], 0, 0, 0);
      }
    }

    if (jt < jtmax) packV(nxt, vra, vrb);

    __syncthreads();
  }

  // ---- epilogue: normalize by O5 row-sums, write ----
  #pragma unroll
  for (int r = 0; r < 4; ++r) {
    float inv = 1.f / O5[r];
    int qrow = qt * 64 + w * 16 + quad * 4 + r;
    size_t gb = ((size_t)qrow * BSZ + b) * 1024 + h * 64;
    #pragma unroll
    for (int ntd = 0; ntd < 4; ++ntd)
      avb[gb + ntd * 16 + l15] = (short)f2bf(O[ntd][r] * inv);
  }
}

// ---------------------------------------------------------------------------
extern "C" void kernel_launch(void* const* d_in, const int* in_sizes, int n_in,
                              void* d_out, int out_size, void* d_ws, size_t ws_size,
                              hipStream_t stream) {
  const float* inputs  = (const float*)d_in[0];
  const float* pos_emb = (const float*)d_in[1];
  const float* full_in = (const float*)d_in[2];
  const float* u       = (const float*)d_in[3];
  const float* v       = (const float*)d_in[4];
  const float* W_kv    = (const float*)d_in[6];
  const float* b_kv    = (const float*)d_in[7];
  const float* W_q     = (const float*)d_in[8];
  const float* b_q     = (const float*)d_in[9];
  const float* W_pos   = (const float*)d_in[10];
  const float* b_pos   = (const float*)d_in[11];
  const float* W_proj  = (const float*)d_in[12];
  const float* b_proj  = (const float*)d_in[13];
  float* out = (float*)d_out;

  char* ws = (char*)d_ws;
  short* fi_bf   = (short*)(ws + 0);          // 8192x1024 bf16  16 MB
  short* in_bf   = (short*)(ws + 16777216);   // 4096x1024 bf16   8 MB
  short* pe_bf   = (short*)(ws + 25165824);   // 1024x1024 bf16   2 MB
  short* Wkv_t   = (short*)(ws + 27262976);   // 2048x1024 bf16   4 MB
  short* Wq_t    = (short*)(ws + 31457280);   // 1024x1024 bf16   2 MB
  short* Wpos_t  = (short*)(ws + 33554432);   // 1024x1024 bf16   2 MB
  short* Wproj_t = (short*)(ws + 35651584);   // 1024x1024 bf16   2 MB
  short* kv_bf   = (short*)(ws + 37748736);   // 8192x2048 bf16  32 MB
  float* q_f32   = (float*)(ws + 71303168);   // 4096x1024 fp32  16 MB
  short* r_bf    = (short*)(ws + 88080384);   // 1024x1024 bf16   2 MB
  short* av_bf   = (short*)(ws + 90177536);   // 4096x1024 bf16   8 MB

  prep_kernel<<<7936, 256, 0, stream>>>(full_in, fi_bf, inputs, in_bf,
                                        pos_emb, pe_bf, W_kv, Wkv_t, W_q, Wq_t,
                                        W_pos, Wpos_t, W_proj, Wproj_t);

  proj_kv8_kernel<<<256, 512, 0, stream>>>(fi_bf, Wkv_t, b_kv, kv_bf);

  proj_qr_kernel<<<320, 256, 0, stream>>>(in_bf, Wq_t, b_q, q_f32,
                                          pe_bf, Wpos_t, b_pos, r_bf);

  attn_mfma_kernel<<<dim3(NH, 8, BSZ), 256, 0, stream>>>(q_f32, kv_bf, r_bf,
                                                         u, v, av_bf);

  out_gemm_kernel<<<256, 256, 0, stream>>>(av_bf, Wproj_t, b_proj, out);
}

// Round 10
// 283.532 us; speedup vs baseline: 1.2784x; 1.0064x over previous
//
#include <hip/hip_runtime.h>

#define CUR 512
#define FULLS 1024
#define BSZ 8
#define DIMM 1024
#define NH 16
#define HD 64

typedef __attribute__((ext_vector_type(8))) short short8;
typedef __attribute__((ext_vector_type(4))) float floatx4;

__device__ __forceinline__ unsigned short f2bf(float x) {
  unsigned int u = __float_as_uint(x);
  unsigned int r = (u + 0x7fffu + ((u >> 16) & 1u)) >> 16;
  return (unsigned short)r;
}
__device__ __forceinline__ float bf2f(unsigned short h) {
  return __uint_as_float(((unsigned int)h) << 16);
}

__device__ __forceinline__ void async16(void* lds, const void* g) {
  __builtin_amdgcn_global_load_lds(
      (const __attribute__((address_space(1))) unsigned int*)g,
      (__attribute__((address_space(3))) unsigned int*)lds, 16, 0, 0);
}

// ---------------------------------------------------------------------------
// Fused prep: all fp32->bf16 casts + weight transpose-casts in ONE launch.
// ---------------------------------------------------------------------------
__global__ __launch_bounds__(256)
void prep_kernel(const float* __restrict__ fi, short* __restrict__ fi_bf,
                 const float* __restrict__ inp, short* __restrict__ in_bf,
                 const float* __restrict__ pe, short* __restrict__ pe_bf,
                 const float* __restrict__ Wkv, short* __restrict__ Wkv_t,
                 const float* __restrict__ Wq, short* __restrict__ Wq_t,
                 const float* __restrict__ Wpos, short* __restrict__ Wpos_t,
                 const float* __restrict__ Wproj, short* __restrict__ Wproj_t) {
  __shared__ float t[64][65];
  const int blk = blockIdx.x;
  const int tid = threadIdx.x;
  if (blk < 6656) {
    const float* x; short* y; int base;
    if (blk < 4096)      { x = fi;  y = fi_bf; base = blk; }
    else if (blk < 6144) { x = inp; y = in_bf; base = blk - 4096; }
    else                 { x = pe;  y = pe_bf; base = blk - 6144; }
    int i = (base * 256 + tid) * 8;
    float a[8];
    *(float4*)&a[0] = *(const float4*)&x[i];
    *(float4*)&a[4] = *(const float4*)&x[i + 4];
    short8 o;
    #pragma unroll
    for (int j = 0; j < 8; ++j) o[j] = f2bf(a[j]);
    *(short8*)&y[i] = o;
    return;
  }
  const float* W; short* Wt; int N, t2;
  if (blk < 7168)      { W = Wkv;   Wt = Wkv_t;   N = 2048; t2 = blk - 6656; }
  else if (blk < 7424) { W = Wq;    Wt = Wq_t;    N = 1024; t2 = blk - 7168; }
  else if (blk < 7680) { W = Wpos;  Wt = Wpos_t;  N = 1024; t2 = blk - 7424; }
  else                 { W = Wproj; Wt = Wproj_t; N = 1024; t2 = blk - 7680; }
  const int K = 1024;
  const int nx = N / 64;
  const int n0 = (t2 % nx) * 64, k0 = (t2 / nx) * 64;
  #pragma unroll
  for (int r = 0; r < 4; ++r) {
    int f = tid + r * 256;
    int row = f >> 4, c = (f & 15) * 4;
    float4 v = *(const float4*)&W[(size_t)(k0 + row) * N + n0 + c];
    t[c + 0][row] = v.x; t[c + 1][row] = v.y;
    t[c + 2][row] = v.z; t[c + 3][row] = v.w;
  }
  __syncthreads();
  #pragma unroll
  for (int r = 0; r < 2; ++r) {
    int f = tid + r * 256;
    int row = f >> 3, c = (f & 7) * 8;
    short8 o;
    #pragma unroll
    for (int j = 0; j < 8; ++j) o[j] = f2bf(t[row][c + j]);
    *(short8*)&Wt[(size_t)(n0 + row) * K + k0 + c] = o;
  }
}

// ---------------------------------------------------------------------------
// bf16 MFMA GEMM body (m97 structure, 128x128 tile) — q/r/out GEMMs.
// ---------------------------------------------------------------------------
__device__ __forceinline__
void gemm_body(short* As, short* Bs,
               const short* __restrict__ A, const short* __restrict__ Bt,
               const float* __restrict__ bias, void* __restrict__ Cp,
               int M, int N, int K, int out_bf16, int bx, int by) {
  const int tid = threadIdx.x;
  const int w = tid >> 6, lane = tid & 63, l15 = lane & 15, quad = lane >> 4;
  const int m0 = by * 128, n0 = bx * 128;
  const int wm = (w & 1) * 64, wn = (w >> 1) * 64;

  floatx4 acc[4][4];
  #pragma unroll
  for (int i = 0; i < 4; ++i)
    #pragma unroll
    for (int j = 0; j < 4; ++j) acc[i][j] = (floatx4){0.f, 0.f, 0.f, 0.f};

  for (int k0 = 0; k0 < K; k0 += 32) {
    __syncthreads();
    #pragma unroll
    for (int rnd = 0; rnd < 2; ++rnd) {
      int fb = rnd * 256 + w * 64;
      int f = fb + lane;
      int row = f >> 2, c = f & 3;
      int cs = (c ^ (row & 3)) * 8;
      async16(As + fb * 8, &A[(size_t)(m0 + row) * K + k0 + cs]);
      async16(Bs + fb * 8, &Bt[(size_t)(n0 + row) * K + k0 + cs]);
    }
    __syncthreads();
    short8 af[4], bf[4];
    #pragma unroll
    for (int t = 0; t < 4; ++t) {
      int swz = ((quad ^ (l15 & 3)) * 8);
      af[t] = *(const short8*)&As[(wm + t * 16 + l15) * 32 + swz];
      bf[t] = *(const short8*)&Bs[(wn + t * 16 + l15) * 32 + swz];
    }
    #pragma unroll
    for (int mt = 0; mt < 4; ++mt)
      #pragma unroll
      for (int nt = 0; nt < 4; ++nt)
        acc[mt][nt] = __builtin_amdgcn_mfma_f32_16x16x32_bf16(
            af[mt], bf[nt], acc[mt][nt], 0, 0, 0);
  }

  #pragma unroll
  for (int mt = 0; mt < 4; ++mt)
    #pragma unroll
    for (int nt = 0; nt < 4; ++nt)
      #pragma unroll
      for (int r = 0; r < 4; ++r) {
        int row = m0 + wm + mt * 16 + quad * 4 + r;
        int col = n0 + wn + nt * 16 + l15;
        float v = acc[mt][nt][r] + bias[col];
        if (out_bf16) ((short*)Cp)[(size_t)row * N + col] = (short)f2bf(v);
        else          ((float*)Cp)[(size_t)row * N + col] = v;
      }
}

// ---------------------------------------------------------------------------
// kv-only 256x256-tile 8-phase bf16 GEMM. 256 blocks = one dispatch round.
// R10: template-exact lgkmcnt(0) drain after each pre-MFMA barrier (m201).
// ---------------------------------------------------------------------------
__global__ __launch_bounds__(512, 2)
void proj_kv8_kernel(const short* __restrict__ A, const short* __restrict__ Bt,
                     const float* __restrict__ bias, short* __restrict__ Cp) {
  __shared__ __align__(16) short As[2][2][128 * 64];
  __shared__ __align__(16) short Bs[2][2][128 * 64];

  const int blk = blockIdx.x;
  const int xcd = blk & 7, l = blk >> 3;
  const int bx = (xcd & 1) * 4 + (l & 3);
  const int by = (xcd >> 1) * 8 + (l >> 2);
  const int N = 2048;

  const int tid = threadIdx.x;
  const int w = tid >> 6, lane = tid & 63, l15 = lane & 15, quad = lane >> 4;
  const int wmi = w >> 2, wni = w & 3;
  const int m0 = by * 256, n0 = bx * 256;
  const int brow0 = (wni & 1) * 64;
  constexpr int NT = 16;

  auto stage = [&](short* dst, const short* src) {
    #pragma unroll
    for (int rnd = 0; rnd < 2; ++rnd) {
      int fb = rnd * 512 + w * 64;
      int f = fb + lane;
      int row = f >> 3, c = f & 7;
      async16(dst + fb * 8, src + (size_t)row * 1024 + ((c ^ (row & 7)) << 3));
    }
  };
  auto srcA = [&](int tt, int h) { return A + ((size_t)(m0 + h * 128)) * 1024 + tt * 64; };
  auto srcB = [&](int tt, int h) { return Bt + ((size_t)(n0 + h * 128)) * 1024 + tt * 64; };

  stage(As[0][0], srcA(0, 0));
  stage(Bs[0][0], srcB(0, 0));
  stage(Bs[0][1], srcB(0, 1));
  stage(As[0][1], srcA(0, 1));
  stage(As[1][0], srcA(1, 0));
  stage(Bs[1][0], srcB(1, 0));
  stage(Bs[1][1], srcB(1, 1));
  asm volatile("s_waitcnt vmcnt(6)" ::: "memory");
  asm volatile("s_barrier" ::: "memory");

  floatx4 acc[8][4];
  #pragma unroll
  for (int i = 0; i < 8; ++i)
    #pragma unroll
    for (int j = 0; j < 4; ++j) acc[i][j] = (floatx4){0.f, 0.f, 0.f, 0.f};

  short8 af[4][2], bf0[2][2], bf1[2][2];

  #pragma unroll 1
  for (int t = 0; t < NT; ++t) {
    const int cur = t & 1, nxt = cur ^ 1;
    short* Ac = As[cur][wmi];
    short* Bc = Bs[cur][wni >> 1];

    #pragma unroll
    for (int mt = 0; mt < 4; ++mt) {
      int r = mt * 16 + l15;
      #pragma unroll
      for (int ks = 0; ks < 2; ++ks)
        af[mt][ks] = *(const short8*)&Ac[r * 64 + ((((ks << 2) + quad) ^ (r & 7)) << 3)];
    }
    #pragma unroll
    for (int nt = 0; nt < 2; ++nt) {
      int r = brow0 + nt * 16 + l15;
      #pragma unroll
      for (int ks = 0; ks < 2; ++ks)
        bf0[nt][ks] = *(const short8*)&Bc[r * 64 + ((((ks << 2) + quad) ^ (r & 7)) << 3)];
    }
    if (t + 1 < NT) stage(As[nxt][1], srcA(t + 1, 1));
    asm volatile("s_barrier" ::: "memory");
    asm volatile("s_waitcnt lgkmcnt(0)" ::: "memory");
    __builtin_amdgcn_sched_barrier(0);
    __builtin_amdgcn_s_setprio(1);
    #pragma unroll
    for (int mt = 0; mt < 4; ++mt)
      #pragma unroll
      for (int nt = 0; nt < 2; ++nt)
        #pragma unroll
        for (int ks = 0; ks < 2; ++ks)
          acc[mt][nt] = __builtin_amdgcn_mfma_f32_16x16x32_bf16(
              af[mt][ks], bf0[nt][ks], acc[mt][nt], 0, 0, 0);
    __builtin_amdgcn_s_setprio(0);
    __builtin_amdgcn_sched_barrier(0);
    asm volatile("s_barrier" ::: "memory");

    #pragma unroll
    for (int nt = 0; nt < 2; ++nt) {
      int r = brow0 + 32 + nt * 16 + l15;
      #pragma unroll
      for (int ks = 0; ks < 2; ++ks)
        bf1[nt][ks] = *(const short8*)&Bc[r * 64 + ((((ks << 2) + quad) ^ (r & 7)) << 3)];
    }
    asm volatile("s_barrier" ::: "memory");
    asm volatile("s_waitcnt lgkmcnt(0)" ::: "memory");
    __builtin_amdgcn_sched_barrier(0);
    __builtin_amdgcn_s_setprio(1);
    #pragma unroll
    for (int mt = 0; mt < 4; ++mt)
      #pragma unroll
      for (int nt = 0; nt < 2; ++nt)
        #pragma unroll
        for (int ks = 0; ks < 2; ++ks)
          acc[mt][nt + 2] = __builtin_amdgcn_mfma_f32_16x16x32_bf16(
              af[mt][ks], bf1[nt][ks], acc[mt][nt + 2], 0, 0, 0);
    __builtin_amdgcn_s_setprio(0);
    __builtin_amdgcn_sched_barrier(0);
    asm volatile("s_barrier" ::: "memory");

    #pragma unroll
    for (int mt = 0; mt < 4; ++mt) {
      int r = 64 + mt * 16 + l15;
      #pragma unroll
      for (int ks = 0; ks < 2; ++ks)
        af[mt][ks] = *(const short8*)&Ac[r * 64 + ((((ks << 2) + quad) ^ (r & 7)) << 3)];
    }
    if (t + 2 < NT) stage(Bs[cur][0], srcB(t + 2, 0));
    asm volatile("s_barrier" ::: "memory");
    asm volatile("s_waitcnt lgkmcnt(0)" ::: "memory");
    __builtin_amdgcn_sched_barrier(0);
    __builtin_amdgcn_s_setprio(1);
    #pragma unroll
    for (int mt = 0; mt < 4; ++mt)
      #pragma unroll
      for (int nt = 0; nt < 2; ++nt)
        #pragma unroll
        for (int ks = 0; ks < 2; ++ks)
          acc[mt + 4][nt + 2] = __builtin_amdgcn_mfma_f32_16x16x32_bf16(
              af[mt][ks], bf1[nt][ks], acc[mt + 4][nt + 2], 0, 0, 0);
    __builtin_amdgcn_s_setprio(0);
    __builtin_amdgcn_sched_barrier(0);
    asm volatile("s_barrier" ::: "memory");

    if (t + 2 < NT) {
      stage(Bs[cur][1], srcB(t + 2, 1));
      stage(As[cur][0], srcA(t + 2, 0));
    }
    __builtin_amdgcn_s_setprio(1);
    #pragma unroll
    for (int mt = 0; mt < 4; ++mt)
      #pragma unroll
      for (int nt = 0; nt < 2; ++nt)
        #pragma unroll
        for (int ks = 0; ks < 2; ++ks)
          acc[mt + 4][nt] = __builtin_amdgcn_mfma_f32_16x16x32_bf16(
              af[mt][ks], bf0[nt][ks], acc[mt + 4][nt], 0, 0, 0);
    __builtin_amdgcn_s_setprio(0);
    __builtin_amdgcn_sched_barrier(0);
    if (t < NT - 2) {
      asm volatile("s_waitcnt vmcnt(6)" ::: "memory");
      asm volatile("s_barrier" ::: "memory");
    } else if (t == NT - 2) {
      asm volatile("s_waitcnt vmcnt(0)" ::: "memory");
      asm volatile("s_barrier" ::: "memory");
    }
  }

  #pragma unroll
  for (int mt = 0; mt < 8; ++mt)
    #pragma unroll
    for (int nt = 0; nt < 4; ++nt)
      #pragma unroll
      for (int r = 0; r < 4; ++r) {
        int row = m0 + wmi * 128 + mt * 16 + quad * 4 + r;
        int col = n0 + wni * 64 + nt * 16 + l15;
        float v = acc[mt][nt][r] + bias[col];
        Cp[(size_t)row * N + col] = (short)f2bf(v);
      }
}

__global__ __launch_bounds__(256)
void proj_qr_kernel(const short* __restrict__ in_bf, const short* __restrict__ Wq_t,
                    const float* __restrict__ b_q, float* __restrict__ q_f32,
                    const short* __restrict__ pe_bf, const short* __restrict__ Wpos_t,
                    const float* __restrict__ b_pos, short* __restrict__ r_bf) {
  __shared__ short As[128 * 32];
  __shared__ short Bs[128 * 32];
  const int blk = blockIdx.x;
  if (blk < 256)
    gemm_body(As, Bs, in_bf, Wq_t, b_q, q_f32, 4096, 1024, 1024, 0,
              blk & 7, blk >> 3);
  else {
    int tb = blk - 256;
    gemm_body(As, Bs, pe_bf, Wpos_t, b_pos, r_bf, 1024, 1024, 1024, 1,
              tb & 7, tb >> 3);
  }
}

__global__ __launch_bounds__(256)
void out_gemm_kernel(const short* __restrict__ av_bf, const short* __restrict__ Wproj_t,
                     const float* __restrict__ b_proj, float* __restrict__ out) {
  __shared__ short As[128 * 32];
  __shared__ short Bs[128 * 32];
  gemm_body(As, Bs, av_bf, Wproj_t, b_proj, out, 4096, 1024, 1024, 0,
            blockIdx.x % 8, blockIdx.x / 8);
}

// ---------------------------------------------------------------------------
// Pipelined MFMA flash attention (R4/R9 proven structure, wave-local P):
//  - K/R staged via async16 one iteration ahead (LDS-fed MFMA operands)
//  - post-prologue __syncthreads (closes latent Rs[0] WAR window)
//  - row-sums via ones-MFMA into O5
//  - R10: T5 setprio(1) around MFMA clusters (m191 attn-positive regime:
//    multiple independent blocks/CU, waves at different phases)
// ---------------------------------------------------------------------------
__global__ __launch_bounds__(256, 2)
void attn_mfma_kernel(const float* __restrict__ qf, const short* __restrict__ kvb,
                      const short* __restrict__ rb, const float* __restrict__ um,
                      const float* __restrict__ vm, short* __restrict__ avb) {
  const int h = blockIdx.x, qt = blockIdx.y, b = blockIdx.z;
  const int tid = threadIdx.x;
  const int w = tid >> 6, lane = tid & 63, l15 = lane & 15, quad = lane >> 4;
  const float SCL2E = 0.125f * 1.44269504089f;   // fold scale + log2(e) into q

  __shared__ short Ks[2][64 * 64];         // [buf][row][chunk-swizzled d]
  __shared__ short Rs[2][64 * 64];         // [buf][row][chunk-swizzled d]
  __shared__ unsigned int Vt[2][64 * 32];  // [buf][d][key-pair], chunk-swizzled
  __shared__ short Pb[2][64 * 69];         // Ptilde chunks (bf16), stride 69
  __shared__ short Pt[4][16 * 72];         // per-wave P (bf16)

  const int jtmax = qt + 8;

  // ---- Q fragments (A-layout), u/v pre-added, pre-scaled, bf16 ----
  short8 qu_[2], qv_[2];
  {
    int qrow = qt * 64 + w * 16 + l15;
    size_t gbase = ((size_t)qrow * BSZ + b) * 1024 + h * 64;
    #pragma unroll
    for (int ks = 0; ks < 2; ++ks) {
      int d0 = ks * 32 + quad * 8;
      float qa[8], ua[8], va[8];
      *(float4*)&qa[0] = *(const float4*)&qf[gbase + d0];
      *(float4*)&qa[4] = *(const float4*)&qf[gbase + d0 + 4];
      *(float4*)&ua[0] = *(const float4*)&um[h * 64 + d0];
      *(float4*)&ua[4] = *(const float4*)&um[h * 64 + d0 + 4];
      *(float4*)&va[0] = *(const float4*)&vm[h * 64 + d0];
      *(float4*)&va[4] = *(const float4*)&vm[h * 64 + d0 + 4];
      #pragma unroll
      for (int j = 0; j < 8; ++j) {
        qu_[ks][j] = f2bf((qa[j] + ua[j]) * SCL2E);
        qv_[ks][j] = f2bf((qa[j] + va[j]) * SCL2E);
      }
    }
  }

  // ---- staging helpers (async16: dest lane-contiguous, source swizzled) ----
  auto stage_K = [&](int buf, int jt) {
    #pragma unroll
    for (int rnd = 0; rnd < 2; ++rnd) {
      int fb = rnd * 256 + w * 64;
      int f = fb + lane;
      int row = f >> 3, c = f & 7;
      int cs = (c ^ (row & 7)) * 8;
      async16(&Ks[buf][fb * 8],
              &kvb[((size_t)(jt * 64 + row) * BSZ + b) * 2048 + h * 64 + cs]);
    }
  };
  auto stage_R = [&](int buf, int p0) {
    #pragma unroll
    for (int rnd = 0; rnd < 2; ++rnd) {
      int fb = rnd * 256 + w * 64;
      int f = fb + lane;
      int row = f >> 3, c = f & 7;
      int cs = (c ^ (row & 7)) * 8;
      async16(&Rs[buf][fb * 8], &rb[(size_t)(p0 + row) * 1024 + h * 64 + cs]);
    }
  };
  const int dc = tid & 7, kp = tid >> 3;
  auto loadV = [&](int jt, short8* va, short8* vb) {
    size_t g0 = ((size_t)(jt * 64 + kp * 2) * BSZ + b) * 2048 + 1024 + h * 64 + dc * 8;
    *va = *(const short8*)&kvb[g0];
    *vb = *(const short8*)&kvb[g0 + 2048 * BSZ];
  };
  auto packV = [&](int buf, short8 va, short8 vb) {
    #pragma unroll
    for (int i = 0; i < 8; ++i) {
      int d = dc * 8 + i;
      int swz = (i ^ dc) & 7;
      Vt[buf][d * 32 + (((kp >> 2) ^ swz) * 4) + (kp & 3)] =
          (unsigned int)(unsigned short)va[i] |
          ((unsigned int)(unsigned short)vb[i] << 16);
    }
  };
  auto compute_chunk = [&](int buf, int rbuf) {
    __builtin_amdgcn_s_setprio(1);
    #pragma unroll
    for (int nt = 0; nt < 4; ++nt) {
      floatx4 a = (floatx4){0.f, 0.f, 0.f, 0.f};
      #pragma unroll
      for (int ks = 0; ks < 2; ++ks) {
        short8 bfr = *(const short8*)
            &Rs[rbuf][(nt * 16 + l15) * 64 + (((ks * 4 + quad) ^ (l15 & 7)) * 8)];
        a = __builtin_amdgcn_mfma_f32_16x16x32_bf16(qv_[ks], bfr, a, 0, 0, 0);
      }
      #pragma unroll
      for (int r = 0; r < 4; ++r)
        Pb[buf][(w * 16 + quad * 4 + r) * 69 + nt * 16 + l15] = (short)f2bf(a[r]);
    }
    __builtin_amdgcn_s_setprio(0);
  };

  // ---- prologue ----
  stage_K(0, 0);
  stage_R(0, 448 - qt * 64);
  stage_R(1, 512 - qt * 64);
  short8 vra, vrb;
  loadV(0, &vra, &vrb);
  packV(0, vra, vrb);
  __syncthreads();

  compute_chunk(1, 0);
  // Latent-race fix: jt=0's stage_R(0,...) async-writes Rs[0]; a lagging wave
  // may still be reading Rs[0] above. Separate with a barrier.
  __syncthreads();

  floatx4 O[4], O5;
  O5 = (floatx4){0.f, 0.f, 0.f, 0.f};
  #pragma unroll
  for (int nt = 0; nt < 4; ++nt) O[nt] = (floatx4){0.f, 0.f, 0.f, 0.f};
  short8 ones;
  #pragma unroll
  for (int j = 0; j < 8; ++j) ones[j] = (short)0x3F80;  // bf16 1.0

  for (int jt = 0; jt <= jtmax; ++jt) {
    const int cur = jt & 1, nxt = cur ^ 1;

    if (jt < jtmax) {
      stage_K(nxt, jt + 1);
      loadV(jt + 1, &vra, &vrb);
    }
    if (jt + 1 < jtmax) stage_R(cur, 512 + 64 * (jt + 1 - qt));

    if (jt < jtmax) compute_chunk(cur, nxt);

    // ---- content scores (already in log2 domain via pre-scaled q) ----
    floatx4 S[4];
    __builtin_amdgcn_s_setprio(1);
    #pragma unroll
    for (int nt = 0; nt < 4; ++nt) {
      S[nt] = (floatx4){0.f, 0.f, 0.f, 0.f};
      #pragma unroll
      for (int ks = 0; ks < 2; ++ks) {
        short8 bfr = *(const short8*)
            &Ks[cur][(nt * 16 + l15) * 64 + (((ks * 4 + quad) ^ (l15 & 7)) * 8)];
        S[nt] = __builtin_amdgcn_mfma_f32_16x16x32_bf16(qu_[ks], bfr, S[nt], 0, 0, 0);
      }
    }
    __builtin_amdgcn_s_setprio(0);

    // ---- rel-shift gather + mask + exp2 (no max, no rescale) ----
    #pragma unroll
    for (int nt = 0; nt < 4; ++nt) {
      #pragma unroll
      for (int r = 0; r < 4; ++r) {
        int il = w * 16 + quad * 4 + r;
        int jl = nt * 16 + l15;
        int rel = jl - il + 63;
        float pos = (rel >= 64) ? bf2f((unsigned short)Pb[cur][il * 69 + rel - 64])
                                : bf2f((unsigned short)Pb[nxt][il * 69 + rel]);
        float z = S[nt][r] + pos;
        if (jt == jtmax && jl > il) z = -1e30f;
        S[nt][r] = __builtin_amdgcn_exp2f(z);
      }
    }

    // ---- P -> LDS (wave-local), read back as A-fragments ----
    #pragma unroll
    for (int nt = 0; nt < 4; ++nt)
      #pragma unroll
      for (int r = 0; r < 4; ++r)
        Pt[w][(quad * 4 + r) * 72 + nt * 16 + l15] = (short)f2bf(S[nt][r]);

    short8 pf[2];
    #pragma unroll
    for (int ks = 0; ks < 2; ++ks)
      pf[ks] = *(const short8*)&Pt[w][l15 * 72 + ks * 32 + quad * 8];

    // ---- row-sums via ones-MFMA + O += P @ V ----
    __builtin_amdgcn_s_setprio(1);
    #pragma unroll
    for (int ks = 0; ks < 2; ++ks)
      O5 = __builtin_amdgcn_mfma_f32_16x16x32_bf16(pf[ks], ones, O5, 0, 0, 0);
    #pragma unroll
    for (int ntd = 0; ntd < 4; ++ntd) {
      int d = ntd * 16 + l15;
      int swv = (d ^ (d >> 3)) & 7;
      #pragma unroll
      for (int ks = 0; ks < 2; ++ks) {
        short8 vfr = *(const short8*)&Vt[cur][d * 32 + (((ks * 4 + quad) ^ swv) * 4)];
        O[ntd] = __builtin_amdgcn_mfma_f32_16x16x32_bf16(pf[ks], vfr, O[ntd], 0, 0, 0);
      }
    }
    __builtin_amdgcn_s_setprio(0);

    if (jt < jtmax) packV(nxt, vra, vrb);

    __syncthreads();
  }

  // ---- epilogue: normalize by O5 row-sums, write ----
  #pragma unroll
  for (int r = 0; r < 4; ++r) {
    float inv = 1.f / O5[r];
    int qrow = qt * 64 + w * 16 + quad * 4 + r;
    size_t gb = ((size_t)qrow * BSZ + b) * 1024 + h * 64;
    #pragma unroll
    for (int ntd = 0; ntd < 4; ++ntd)
      avb[gb + ntd * 16 + l15] = (short)f2bf(O[ntd][r] * inv);
  }
}

// ---------------------------------------------------------------------------
extern "C" void kernel_launch(void* const* d_in, const int* in_sizes, int n_in,
                              void* d_out, int out_size, void* d_ws, size_t ws_size,
                              hipStream_t stream) {
  const float* inputs  = (const float*)d_in[0];
  const float* pos_emb = (const float*)d_in[1];
  const float* full_in = (const float*)d_in[2];
  const float* u       = (const float*)d_in[3];
  const float* v       = (const float*)d_in[4];
  const float* W_kv    = (const float*)d_in[6];
  const float* b_kv    = (const float*)d_in[7];
  const float* W_q     = (const float*)d_in[8];
  const float* b_q     = (const float*)d_in[9];
  const float* W_pos   = (const float*)d_in[10];
  const float* b_pos   = (const float*)d_in[11];
  const float* W_proj  = (const float*)d_in[12];
  const float* b_proj  = (const float*)d_in[13];
  float* out = (float*)d_out;

  char* ws = (char*)d_ws;
  short* fi_bf   = (short*)(ws + 0);          // 8192x1024 bf16  16 MB
  short* in_bf   = (short*)(ws + 16777216);   // 4096x1024 bf16   8 MB
  short* pe_bf   = (short*)(ws + 25165824);   // 1024x1024 bf16   2 MB
  short* Wkv_t   = (short*)(ws + 27262976);   // 2048x1024 bf16   4 MB
  short* Wq_t    = (short*)(ws + 31457280);   // 1024x1024 bf16   2 MB
  short* Wpos_t  = (short*)(ws + 33554432);   // 1024x1024 bf16   2 MB
  short* Wproj_t = (short*)(ws + 35651584);   // 1024x1024 bf16   2 MB
  short* kv_bf   = (short*)(ws + 37748736);   // 8192x2048 bf16  32 MB
  float* q_f32   = (float*)(ws + 71303168);   // 4096x1024 fp32  16 MB
  short* r_bf    = (short*)(ws + 88080384);   // 1024x1024 bf16   2 MB
  short* av_bf   = (short*)(ws + 90177536);   // 4096x1024 bf16   8 MB

  prep_kernel<<<7936, 256, 0, stream>>>(full_in, fi_bf, inputs, in_bf,
                                        pos_emb, pe_bf, W_kv, Wkv_t, W_q, Wq_t,
                                        W_pos, Wpos_t, W_proj, Wproj_t);

  proj_kv8_kernel<<<256, 512, 0, stream>>>(fi_bf, Wkv_t, b_kv, kv_bf);

  proj_qr_kernel<<<320, 256, 0, stream>>>(in_bf, Wq_t, b_q, q_f32,
                                          pe_bf, Wpos_t, b_pos, r_bf);

  attn_mfma_kernel<<<dim3(NH, 8, BSZ), 256, 0, stream>>>(q_f32, kv_bf, r_bf,
                                                         u, v, av_bf);

  out_gemm_kernel<<<256, 256, 0, stream>>>(av_bf, Wproj_t, b_proj, out);
}